// Round 9
// baseline (138.948 us; speedup 1.0000x reference)
//
#include <hip/hip_runtime.h>
#include <hip/hip_fp16.h>
#include <cstdint>
#include <cstddef>

#define N_NODES 50000
#define N_EDGES 800000
#define DIM_IN  128
#define DIM_OUT 64

// R8 post-mortem: the FE's global atomicAdd-with-return reserve serializes
// per-counter at the coherence point (~100-200ns each); cost scales with FE
// block count (R7:196/R2:782/R8:391 per counter -> 114/+6/+8 us). R9 removes
// runtime reservation: two-pass radix (hist matrix -> computed offsets),
// ZERO global atomics anywhere.
#define B2SHIFT 8                                   // 256 nodes per bucket
#define B2NODES 256
#define NB2     ((N_NODES + B2NODES - 1) / B2NODES) // 196 buckets
#define EB      4096                                // edges per front-end tile
#define SORTB   ((N_EDGES + EB - 1) / EB)           // 196 tiles
#define NE4     (N_EDGES / 4)                       // 200000 int4 edge groups
#define CAPB    4864                                // slots/bucket (mean 4082 + 12 sigma)
#define GROWS   128                                 // gemm rows per 256t unit (R0/R7 proven)
#define GEMMB   ((N_NODES + GROWS - 1) / GROWS)     // 391 gemm units
#define HSTRIDE 256                                 // hist row stride (ints)
#define NEGRP   ((N_NODES + 31) / 32)               // 1563 kE blocks (32 nodes each)

typedef _Float16 f16x8 __attribute__((ext_vector_type(8)));
typedef float    f32x4 __attribute__((ext_vector_type(4)));

// ---------------------------------------------------------------------------
// k1: dual-role dispatch, 256 threads/block (R7-proven geometry).
//   blocks 0..SORTB-1 : per-tile HISTOGRAM ONLY -> hist[tile][256] (no
//     reserve, no scatter — the serialized global atomics are gone).
//   blocks SORTB..586 : MFMA gemm (R0 verbatim) writing UNSCALED h.
// ---------------------------------------------------------------------------
__global__ __launch_bounds__(256) void k1_histgemm(const int* __restrict__ ei,
                                                   int* __restrict__ hist,
                                                   const float* __restrict__ x,
                                                   const float* __restrict__ W,
                                                   __half* __restrict__ h) {
    const int t = threadIdx.x;
    if (blockIdx.x < SORTB) {
        __shared__ int hcnt[B2NODES];
        const int blk = blockIdx.x;
        hcnt[t] = 0;                         // blockDim == B2NODES
        __syncthreads();
        const int4* dst4 = (const int4*)(ei + N_EDGES);
        const int g0 = blk * (EB / 4);
#pragma unroll
        for (int it = 0; it < EB / 1024; ++it) {
            const int g = g0 + it * 256 + t;
            if (g < NE4) {
                const int4 d = dst4[g];
                atomicAdd(&hcnt[d.x >> B2SHIFT], 1);
                atomicAdd(&hcnt[d.y >> B2SHIFT], 1);
                atomicAdd(&hcnt[d.z >> B2SHIFT], 1);
                atomicAdd(&hcnt[d.w >> B2SHIFT], 1);
            }
        }
        __syncthreads();
        hist[blk * HSTRIDE + t] = hcnt[t];   // plain coalesced store
    } else {
        // ---- gemm unit: h[n,:] = half(x[n,:] @ W), UNSCALED (R0 verbatim) ----
        // MFMA 16x16x32_f16: A[m=lane&15][k=quad*8+j]; B[k][n=lane&15];
        // C/D: row=quad*4+reg, col=lane&15 (validated R6-R10).
        const int u = blockIdx.x - SORTB;
        const int w = t >> 6;
        const int l = t & 63;
        const int q = l >> 4;
        const int m16 = l & 15;

        f16x8 bf[4][4];
#pragma unroll
        for (int kc = 0; kc < 4; ++kc)
#pragma unroll
            for (int ct = 0; ct < 4; ++ct) {
                const float* wp = W + (size_t)(kc * 32 + q * 8) * DIM_OUT + ct * 16 + m16;
                f16x8 v;
#pragma unroll
                for (int j = 0; j < 8; ++j) v[j] = (_Float16)wp[(size_t)j * DIM_OUT];
                bf[kc][ct] = v;
            }

        const int base = u * GROWS + w * 32;
#pragma unroll
        for (int rt = 0; rt < 2; ++rt) {
            const int m0 = base + rt * 16;
            int mrow = m0 + m16;
            if (mrow >= N_NODES) mrow = N_NODES - 1;   // clamp (stores guarded)

            f16x8 af[4];
#pragma unroll
            for (int kc = 0; kc < 4; ++kc) {
                const float4* xp = (const float4*)(x + (size_t)mrow * DIM_IN + kc * 32 + q * 8);
                const float4 p0 = xp[0], p1 = xp[1];
                f16x8 a;
                a[0] = (_Float16)p0.x; a[1] = (_Float16)p0.y;
                a[2] = (_Float16)p0.z; a[3] = (_Float16)p0.w;
                a[4] = (_Float16)p1.x; a[5] = (_Float16)p1.y;
                a[6] = (_Float16)p1.z; a[7] = (_Float16)p1.w;
                af[kc] = a;
            }

            f32x4 acc[4];
#pragma unroll
            for (int ct = 0; ct < 4; ++ct) acc[ct] = (f32x4){0.f, 0.f, 0.f, 0.f};
#pragma unroll
            for (int kc = 0; kc < 4; ++kc)
#pragma unroll
                for (int ct = 0; ct < 4; ++ct)
                    acc[ct] = __builtin_amdgcn_mfma_f32_16x16x32_f16(af[kc], bf[kc][ct], acc[ct], 0, 0, 0);

#pragma unroll
            for (int reg = 0; reg < 4; ++reg) {
                const int r = m0 + q * 4 + reg;
                if (r < N_NODES) {
#pragma unroll
                    for (int ct = 0; ct < 4; ++ct)
                        h[(size_t)r * DIM_OUT + ct * 16 + m16] = __float2half(acc[ct][reg]);
                }
            }
        }
    }
}

// ---------------------------------------------------------------------------
// kScatter: one block per tile (512 threads). Deterministic placement:
//   colbase[b] = sum over prior tiles of hist[t][b] (coalesced L2-hot reads,
//   NO atomics) -> row scan -> LDS counting sort (R5-proven) -> computed
//   coalesced dump into pairs.
// ---------------------------------------------------------------------------
__global__ __launch_bounds__(512) void kScatter(const int* __restrict__ ei,
                                                const int* __restrict__ hist,
                                                unsigned* __restrict__ pairs) {
    __shared__ int hrow[B2NODES];
    __shared__ int excl[B2NODES];
    __shared__ int curb[B2NODES];
    __shared__ int gbase[B2NODES];
    __shared__ int wsum[4];
    __shared__ unsigned lpair[EB];           // 16 KB
    const int blk = blockIdx.x, t = threadIdx.x;
    const int ecnt = min(EB, N_EDGES - blk * EB);

    if (t < B2NODES) {
        hrow[t] = hist[blk * HSTRIDE + t];
        int s = 0;
        for (int tt = 0; tt < blk; ++tt)     // coalesced per iteration, L2-hot
            s += hist[tt * HSTRIDE + t];
        gbase[t] = s;                        // colbase for now
    }
    __syncthreads();
    if (t < B2NODES) {                       // 256-bin exclusive scan of hrow
        const int lane = t & 63;
        const int v = hrow[t];
        int xs = v;
#pragma unroll
        for (int off = 1; off < 64; off <<= 1) {
            int y = __shfl_up(xs, off);
            if (lane >= off) xs += y;
        }
        excl[t] = xs;
        if (lane == 63) wsum[t >> 6] = xs;
    }
    __syncthreads();
    if (t == 0) {
        int acc = 0;
#pragma unroll
        for (int w2 = 0; w2 < 4; ++w2) { const int v2 = wsum[w2]; wsum[w2] = acc; acc += v2; }
    }
    __syncthreads();
    if (t < B2NODES) {
        const int e = excl[t] - hrow[t] + wsum[t >> 6];
        excl[t] = e;
        curb[t] = e;
        gbase[t] = t * CAPB + gbase[t] - e;  // dst = gbase[b] + j
    }
    __syncthreads();
    {   // LDS counting-sort scatter (R5-proven): 2 int4 groups per thread
        const int4* src4 = (const int4*)ei;
        const int4* dst4 = (const int4*)(ei + N_EDGES);
        const int gA = blk * (EB / 4) + t;
        const int gB = gA + 512;
        const int glim = blk * (EB / 4) + (ecnt >> 2);
        if (gA < glim && gA < NE4) {
            const int4 dv = dst4[gA]; const int4 sv = src4[gA];
            int b, p;
            b = dv.x >> B2SHIFT; p = atomicAdd(&curb[b], 1);
            lpair[p] = ((unsigned)sv.x << 16) | (unsigned)dv.x;
            b = dv.y >> B2SHIFT; p = atomicAdd(&curb[b], 1);
            lpair[p] = ((unsigned)sv.y << 16) | (unsigned)dv.y;
            b = dv.z >> B2SHIFT; p = atomicAdd(&curb[b], 1);
            lpair[p] = ((unsigned)sv.z << 16) | (unsigned)dv.z;
            b = dv.w >> B2SHIFT; p = atomicAdd(&curb[b], 1);
            lpair[p] = ((unsigned)sv.w << 16) | (unsigned)dv.w;
        }
        if (gB < glim && gB < NE4) {
            const int4 dv = dst4[gB]; const int4 sv = src4[gB];
            int b, p;
            b = dv.x >> B2SHIFT; p = atomicAdd(&curb[b], 1);
            lpair[p] = ((unsigned)sv.x << 16) | (unsigned)dv.x;
            b = dv.y >> B2SHIFT; p = atomicAdd(&curb[b], 1);
            lpair[p] = ((unsigned)sv.y << 16) | (unsigned)dv.y;
            b = dv.z >> B2SHIFT; p = atomicAdd(&curb[b], 1);
            lpair[p] = ((unsigned)sv.z << 16) | (unsigned)dv.z;
            b = dv.w >> B2SHIFT; p = atomicAdd(&curb[b], 1);
            lpair[p] = ((unsigned)sv.w << 16) | (unsigned)dv.w;
        }
    }
    __syncthreads();
    for (int j = t; j < ecnt; j += 512) {    // computed coalesced dump
        const unsigned p = lpair[j];
        const int b = (int)(p & 0xFFFFu) >> B2SHIFT;
        const int dst = gbase[b] + j;
        if (dst < (b + 1) * CAPB) pairs[dst] = p;   // paranoia guard
    }
}

// ---------------------------------------------------------------------------
// Sort (R4/R7 proven interior): one block per 256-node bucket (512 threads).
// count now comes from summing hist[:, b] (196 L2 reads + block reduce).
// ---------------------------------------------------------------------------
__global__ __launch_bounds__(512) void kSort(const unsigned* __restrict__ pairs,
                                             const int* __restrict__ hist,
                                             unsigned short* __restrict__ csr,
                                             int2* __restrict__ nodeoff2,
                                             __half* __restrict__ h) {
    __shared__ int cnt[B2NODES];
    __shared__ int cur[B2NODES];
    __shared__ float sdinv[B2NODES];
    __shared__ int wsum[4];
    __shared__ int btot;
    __shared__ unsigned short lcsr[CAPB];    // 9.7 KB
    const int b = blockIdx.x, t = threadIdx.x;
    const int eb = b * CAPB;

    {   // bucket total = sum over tiles of hist[t][b]
        int v = 0;
        for (int tt = t; tt < SORTB; tt += 512) v += hist[tt * HSTRIDE + b];
#pragma unroll
        for (int off = 32; off > 0; off >>= 1) v += __shfl_xor(v, off);
        if ((t & 63) == 0) wsum[t >> 6] = v;
        __syncthreads();
        if (t == 0) btot = min(wsum[0] + wsum[1] + wsum[2] + wsum[3], CAPB);
    }
    if (t < B2NODES) cnt[t] = 0;
    __syncthreads();
    const int count = btot;
    const int ee = eb + count;

    {   // count per node
        int i = eb + t;
        for (; i + 1536 < ee; i += 2048) {
            const unsigned p0 = pairs[i];
            const unsigned p1 = pairs[i + 512];
            const unsigned p2 = pairs[i + 1024];
            const unsigned p3 = pairs[i + 1536];
            atomicAdd(&cnt[p0 & (B2NODES - 1)], 1);
            atomicAdd(&cnt[p1 & (B2NODES - 1)], 1);
            atomicAdd(&cnt[p2 & (B2NODES - 1)], 1);
            atomicAdd(&cnt[p3 & (B2NODES - 1)], 1);
        }
        for (; i < ee; i += 512) atomicAdd(&cnt[pairs[i] & (B2NODES - 1)], 1);
    }
    __syncthreads();

    // 256-bin exclusive scan: intra-wave shuffle scan + cross-wave combine
    if (t < B2NODES) {
        const int lane = t & 63;
        const int v = cnt[t];
        int xs = v;
#pragma unroll
        for (int off = 1; off < 64; off <<= 1) {
            int y = __shfl_up(xs, off);
            if (lane >= off) xs += y;
        }
        cur[t] = xs;                         // intra-wave inclusive
        if (lane == 63) wsum[t >> 6] = xs;
    }
    __syncthreads();
    if (t == 0) {
        int acc = 0;
#pragma unroll
        for (int w2 = 0; w2 < 4; ++w2) { const int v2 = wsum[w2]; wsum[w2] = acc; acc += v2; }
    }
    __syncthreads();
    if (t < B2NODES) {
        const int v = cnt[t];
        const int excl = cur[t] - v + wsum[t >> 6];
        sdinv[t] = rsqrtf((float)(v + 1));
        const int n = (b << B2SHIFT) + t;
        if (n < N_NODES) nodeoff2[n] = make_int2(eb + excl, v);
        cur[t] = excl;                       // bucket-local scatter offsets
    }
    __syncthreads();

    for (int i = eb + t; i < ee; i += 512) { // LDS scatter
        const unsigned p = pairs[i];
        const int q = atomicAdd(&cur[p & (B2NODES - 1)], 1);
        lcsr[q] = (unsigned short)(p >> 16);
    }
    __syncthreads();

    {   // coalesced csr dump (2 ushorts per uint store)
        const int cw = (count + 1) >> 1;
        const unsigned* l32 = (const unsigned*)lcsr;
        unsigned* c32 = (unsigned*)(csr + eb);
        for (int i2 = t; i2 < cw; i2 += 512) c32[i2] = l32[i2];
    }
    {   // in-place h-scale for this bucket's 256 nodes (contiguous 32 KB)
        f16x8* h8w = (f16x8*)h;
        for (int idx = t; idx < B2NODES * 8; idx += 512) {
            const int r = idx >> 3;
            const int n = (b << B2SHIFT) + r;
            if (n < N_NODES) {
                const float d = sdinv[r];
                f16x8 v = h8w[(size_t)n * 8 + (idx & 7)];
#pragma unroll
                for (int j = 0; j < 8; ++j) v[j] = (_Float16)((float)v[j] * d);
                h8w[(size_t)n * 8 + (idx & 7)] = v;
            }
        }
    }
}

// ---------------------------------------------------------------------------
// E (R0 verbatim, proven): CSR gather + bias + log_softmax. EIGHTH-wave per
// node: 8 lanes x 16 B f16x8 loads. 32 nodes/block, 1563 blocks.
// ---------------------------------------------------------------------------
__global__ __launch_bounds__(256) void kE_agg(const int2* __restrict__ nodeoff2,
                                              const unsigned short* __restrict__ csr,
                                              const __half* __restrict__ h,
                                              const float* __restrict__ bvec,
                                              float* __restrict__ out) {
    const int t = threadIdx.x;
    const int ew = t >> 3, sl = t & 7;       // eighth-wave id / sub-lane
    const int n = blockIdx.x * 32 + ew;
    if (n >= N_NODES) return;                // unit-uniform guard
    const f16x8* __restrict__ h8 = (const f16x8*)h;

    const int2 off = nodeoff2[n];
    const int s0 = off.x, s1 = off.x + off.y;

    const f16x8 hv = h8[(size_t)n * 8 + sl]; // self-loop term (scaled)
    float a[8];
#pragma unroll
    for (int j = 0; j < 8; ++j) a[j] = (float)hv[j];

    int i = s0;
    for (; i + 4 <= s1; i += 4) {
        const int c0 = csr[i + 0];
        const int c1 = csr[i + 1];
        const int c2 = csr[i + 2];
        const int c3 = csr[i + 3];
        const f16x8 v0 = h8[(size_t)c0 * 8 + sl];
        const f16x8 v1 = h8[(size_t)c1 * 8 + sl];
        const f16x8 v2 = h8[(size_t)c2 * 8 + sl];
        const f16x8 v3 = h8[(size_t)c3 * 8 + sl];
#pragma unroll
        for (int j = 0; j < 8; ++j)
            a[j] += (float)v0[j] + (float)v1[j] + (float)v2[j] + (float)v3[j];
    }
    for (; i < s1; ++i) {
        const f16x8 v0 = h8[(size_t)csr[i] * 8 + sl];
#pragma unroll
        for (int j = 0; j < 8; ++j) a[j] += (float)v0[j];
    }

    const float4 b0 = *(const float4*)&bvec[8 * sl];
    const float4 b1 = *(const float4*)&bvec[8 * sl + 4];
    const float di = rsqrtf((float)(off.y + 1));
    float v[8];
    v[0] = a[0] * di + b0.x; v[1] = a[1] * di + b0.y;
    v[2] = a[2] * di + b0.z; v[3] = a[3] * di + b0.w;
    v[4] = a[4] * di + b1.x; v[5] = a[5] * di + b1.y;
    v[6] = a[6] * di + b1.z; v[7] = a[7] * di + b1.w;

    float m = v[0];
#pragma unroll
    for (int j = 1; j < 8; ++j) m = fmaxf(m, v[j]);
#pragma unroll
    for (int o = 4; o > 0; o >>= 1) m = fmaxf(m, __shfl_xor(m, o));
    float s = 0.f;
#pragma unroll
    for (int j = 0; j < 8; ++j) s += __expf(v[j] - m);
#pragma unroll
    for (int o = 4; o > 0; o >>= 1) s += __shfl_xor(s, o);
    const float ls = m + __logf(s);

    float4 o0, o1;
    o0.x = v[0] - ls; o0.y = v[1] - ls; o0.z = v[2] - ls; o0.w = v[3] - ls;
    o1.x = v[4] - ls; o1.y = v[5] - ls; o1.z = v[6] - ls; o1.w = v[7] - ls;
    *(float4*)&out[(size_t)n * DIM_OUT + 8 * sl]     = o0;
    *(float4*)&out[(size_t)n * DIM_OUT + 8 * sl + 4] = o1;
}

// ---------------------------------------------------------------------------
extern "C" void kernel_launch(void* const* d_in, const int* in_sizes, int n_in,
                              void* d_out, int out_size, void* d_ws, size_t ws_size,
                              hipStream_t stream) {
    const float* x  = (const float*)d_in[0];
    const int*   ei = (const int*)d_in[1];   // [2, E]: row0 = src, row1 = dst
    const float* W  = (const float*)d_in[2];
    const float* b  = (const float*)d_in[3];
    float* out = (float*)d_out;

    // workspace (~13 MB of the 256 MB ws):
    char* ws = (char*)d_ws;
    __half*         h        = (__half*)ws;         ws += (size_t)N_NODES * DIM_OUT * sizeof(__half);
    unsigned*       pairs    = (unsigned*)ws;       ws += (size_t)NB2 * CAPB * sizeof(unsigned);
    unsigned short* csr      = (unsigned short*)ws; ws += (size_t)NB2 * CAPB * sizeof(unsigned short);
    int2*           nodeoff2 = (int2*)ws;           ws += (size_t)N_NODES * sizeof(int2);
    int*            hist     = (int*)ws;            ws += (size_t)SORTB * HSTRIDE * sizeof(int);

    k1_histgemm<<<SORTB + GEMMB, 256, 0, stream>>>(ei, hist, x, W, h);
    kScatter   <<<SORTB, 512, 0, stream>>>(ei, hist, pairs);
    kSort      <<<NB2, 512, 0, stream>>>(pairs, hist, csr, nodeoff2, h);
    kE_agg     <<<NEGRP, 256, 0, stream>>>(nodeoff2, csr, h, b, out);
}

// Round 10
// 121.021 us; speedup vs baseline: 1.1481x; 1.1481x over previous
//
#include <hip/hip_runtime.h>
#include <hip/hip_fp16.h>
#include <cstdint>
#include <cstddef>

#define N_NODES 50000
#define N_EDGES 800000
#define DIM_IN  128
#define DIM_OUT 64

// R9 post-mortem: 2-pass radix cost more than the reserve it removed. R10:
// single-pass FE with FIXED per-(bucket,tile) 64-slot runs — deterministic
// placement from the block-local LDS counter alone. No global atomics, no
// reserve barrier, no histogram pre-pass (halves FE edge reads), no gcnt,
// no k_zero launch. Cell overflow is +9.4 sigma (guarded).
#define B2SHIFT 8                                   // 256 nodes per bucket
#define B2NODES 256
#define NB2     ((N_NODES + B2NODES - 1) / B2NODES) // 196 buckets
#define EB      4096                                // edges per front-end tile
#define SORTB   ((N_EDGES + EB - 1) / EB)           // 196 tiles
#define NE4     (N_EDGES / 4)                       // 200000 int4 edge groups
#define RUNSZ   64                                  // slots per (bucket,tile) cell
#define RUNTOT  (SORTB * RUNSZ)                     // 12544 slots per bucket
#define CAPB    4864                                // lcsr capacity (mean 4082 + 12 sigma)
#define GROWS   128                                 // gemm rows per 256t unit (R0/R7 proven)
#define GEMMB   ((N_NODES + GROWS - 1) / GROWS)     // 391 gemm units
#define HSTRIDE 256                                 // hist row stride (ints)
#define NEGRP   ((N_NODES + 31) / 32)               // 1563 kE blocks (32 nodes each)

typedef _Float16 f16x8 __attribute__((ext_vector_type(8)));
typedef float    f32x4 __attribute__((ext_vector_type(4)));

// ---------------------------------------------------------------------------
// FG: dual-role dispatch, 256 threads/block, NO grid sync.
//   blocks 0..SORTB-1 : SINGLE-PASS front-end. Edge -> bucket b; slot from
//     LDS counter; pairs[b][tile][slot] fixed location. hist row records
//     run lengths for kSort. Zero global atomics, one edge read.
//   blocks SORTB..586 : MFMA gemm (R0 verbatim) writing UNSCALED h.
// ---------------------------------------------------------------------------
__global__ __launch_bounds__(256) void kFG(const int* __restrict__ ei,
                                           int* __restrict__ hist,
                                           unsigned* __restrict__ pairs,
                                           const float* __restrict__ x,
                                           const float* __restrict__ W,
                                           __half* __restrict__ h) {
    const int t = threadIdx.x;
    if (blockIdx.x < SORTB) {
        __shared__ int curb[B2NODES];
        const int blk = blockIdx.x;
        curb[t] = 0;                         // blockDim == B2NODES
        __syncthreads();
        const int4* src4 = (const int4*)ei;
        const int4* dst4 = (const int4*)(ei + N_EDGES);
        const int g0 = blk * (EB / 4);
        const int rbase = blk * RUNSZ;       // this tile's run offset in a bucket
#pragma unroll
        for (int it = 0; it < EB / 1024; ++it) {
            const int g = g0 + it * 256 + t;
            if (g < NE4) {
                const int4 dv = dst4[g];
                const int4 sv = src4[g];
                int b, p;
                b = dv.x >> B2SHIFT; p = atomicAdd(&curb[b], 1);
                if (p < RUNSZ) pairs[(size_t)b * RUNTOT + rbase + p] = ((unsigned)sv.x << 16) | (unsigned)dv.x;
                b = dv.y >> B2SHIFT; p = atomicAdd(&curb[b], 1);
                if (p < RUNSZ) pairs[(size_t)b * RUNTOT + rbase + p] = ((unsigned)sv.y << 16) | (unsigned)dv.y;
                b = dv.z >> B2SHIFT; p = atomicAdd(&curb[b], 1);
                if (p < RUNSZ) pairs[(size_t)b * RUNTOT + rbase + p] = ((unsigned)sv.z << 16) | (unsigned)dv.z;
                b = dv.w >> B2SHIFT; p = atomicAdd(&curb[b], 1);
                if (p < RUNSZ) pairs[(size_t)b * RUNTOT + rbase + p] = ((unsigned)sv.w << 16) | (unsigned)dv.w;
            }
        }
        __syncthreads();
        hist[blk * HSTRIDE + t] = min(curb[t], RUNSZ);   // run lengths
    } else {
        // ---- gemm unit: h[n,:] = half(x[n,:] @ W), UNSCALED (R0 verbatim) ----
        // MFMA 16x16x32_f16: A[m=lane&15][k=quad*8+j]; B[k][n=lane&15];
        // C/D: row=quad*4+reg, col=lane&15 (validated R6-R10).
        const int u = blockIdx.x - SORTB;
        const int w = t >> 6;
        const int l = t & 63;
        const int q = l >> 4;
        const int m16 = l & 15;

        f16x8 bf[4][4];
#pragma unroll
        for (int kc = 0; kc < 4; ++kc)
#pragma unroll
            for (int ct = 0; ct < 4; ++ct) {
                const float* wp = W + (size_t)(kc * 32 + q * 8) * DIM_OUT + ct * 16 + m16;
                f16x8 v;
#pragma unroll
                for (int j = 0; j < 8; ++j) v[j] = (_Float16)wp[(size_t)j * DIM_OUT];
                bf[kc][ct] = v;
            }

        const int base = u * GROWS + w * 32;
#pragma unroll
        for (int rt = 0; rt < 2; ++rt) {
            const int m0 = base + rt * 16;
            int mrow = m0 + m16;
            if (mrow >= N_NODES) mrow = N_NODES - 1;   // clamp (stores guarded)

            f16x8 af[4];
#pragma unroll
            for (int kc = 0; kc < 4; ++kc) {
                const float4* xp = (const float4*)(x + (size_t)mrow * DIM_IN + kc * 32 + q * 8);
                const float4 p0 = xp[0], p1 = xp[1];
                f16x8 a;
                a[0] = (_Float16)p0.x; a[1] = (_Float16)p0.y;
                a[2] = (_Float16)p0.z; a[3] = (_Float16)p0.w;
                a[4] = (_Float16)p1.x; a[5] = (_Float16)p1.y;
                a[6] = (_Float16)p1.z; a[7] = (_Float16)p1.w;
                af[kc] = a;
            }

            f32x4 acc[4];
#pragma unroll
            for (int ct = 0; ct < 4; ++ct) acc[ct] = (f32x4){0.f, 0.f, 0.f, 0.f};
#pragma unroll
            for (int kc = 0; kc < 4; ++kc)
#pragma unroll
                for (int ct = 0; ct < 4; ++ct)
                    acc[ct] = __builtin_amdgcn_mfma_f32_16x16x32_f16(af[kc], bf[kc][ct], acc[ct], 0, 0, 0);

#pragma unroll
            for (int reg = 0; reg < 4; ++reg) {
                const int r = m0 + q * 4 + reg;
                if (r < N_NODES) {
#pragma unroll
                    for (int ct = 0; ct < 4; ++ct)
                        h[(size_t)r * DIM_OUT + ct * 16 + m16] = __float2half(acc[ct][reg]);
                }
            }
        }
    }
}

// ---------------------------------------------------------------------------
// Sort: one block per 256-node bucket (512 threads). Reads the bucket's 196
// guarded runs (contiguous 50 KB, flat loop), counts -> scan -> LDS scatter
// -> coalesced csr dump + nodeoff2 + in-place h *= rsqrt(deg+1).
// Interior logic verbatim R7; only the pairs iteration is run-structured.
// ---------------------------------------------------------------------------
__global__ __launch_bounds__(512) void kSort(const unsigned* __restrict__ pairs,
                                             const int* __restrict__ hist,
                                             unsigned short* __restrict__ csr,
                                             int2* __restrict__ nodeoff2,
                                             __half* __restrict__ h) {
    __shared__ int cnt[B2NODES];
    __shared__ int cur[B2NODES];
    __shared__ float sdinv[B2NODES];
    __shared__ int wsum[4];
    __shared__ int tot;
    __shared__ int hlen[SORTB];
    __shared__ unsigned short lcsr[CAPB];    // 9.7 KB
    const int b = blockIdx.x, t = threadIdx.x;
    const int eb = b * CAPB;
    const unsigned* __restrict__ pb = pairs + (size_t)b * RUNTOT;

    if (t < SORTB) hlen[t] = hist[t * HSTRIDE + b];
    if (t < B2NODES) cnt[t] = 0;
    __syncthreads();

    // count per node over the guarded runs
    for (int f = t; f < RUNTOT; f += 512) {
        if ((f & (RUNSZ - 1)) < hlen[f >> 6])
            atomicAdd(&cnt[pb[f] & (B2NODES - 1)], 1);
    }
    __syncthreads();

    // 256-bin exclusive scan: intra-wave shuffle scan + cross-wave combine
    if (t < B2NODES) {
        const int lane = t & 63;
        const int v = cnt[t];
        int xs = v;
#pragma unroll
        for (int off = 1; off < 64; off <<= 1) {
            int y = __shfl_up(xs, off);
            if (lane >= off) xs += y;
        }
        cur[t] = xs;                         // intra-wave inclusive
        if (lane == 63) wsum[t >> 6] = xs;
    }
    __syncthreads();
    if (t == 0) {
        int acc = 0;
#pragma unroll
        for (int w2 = 0; w2 < 4; ++w2) { const int v2 = wsum[w2]; wsum[w2] = acc; acc += v2; }
        tot = min(acc, CAPB);
    }
    __syncthreads();
    if (t < B2NODES) {
        const int v = cnt[t];
        const int excl = cur[t] - v + wsum[t >> 6];
        sdinv[t] = rsqrtf((float)(v + 1));
        const int n = (b << B2SHIFT) + t;
        if (n < N_NODES) nodeoff2[n] = make_int2(eb + excl, v);
        cur[t] = excl;                       // bucket-local scatter offsets
    }
    __syncthreads();

    // LDS scatter over the same guarded runs (L2-hot second read)
    for (int f = t; f < RUNTOT; f += 512) {
        if ((f & (RUNSZ - 1)) < hlen[f >> 6]) {
            const unsigned p = pb[f];
            const int q = atomicAdd(&cur[p & (B2NODES - 1)], 1);
            if (q < CAPB) lcsr[q] = (unsigned short)(p >> 16);
        }
    }
    __syncthreads();

    {   // coalesced csr dump (2 ushorts per uint store)
        const int cw = (tot + 1) >> 1;
        const unsigned* l32 = (const unsigned*)lcsr;
        unsigned* c32 = (unsigned*)(csr + eb);
        for (int i2 = t; i2 < cw; i2 += 512) c32[i2] = l32[i2];
    }
    {   // in-place h-scale for this bucket's 256 nodes (contiguous 32 KB)
        f16x8* h8w = (f16x8*)h;
        for (int idx = t; idx < B2NODES * 8; idx += 512) {
            const int r = idx >> 3;
            const int n = (b << B2SHIFT) + r;
            if (n < N_NODES) {
                const float d = sdinv[r];
                f16x8 v = h8w[(size_t)n * 8 + (idx & 7)];
#pragma unroll
                for (int j = 0; j < 8; ++j) v[j] = (_Float16)((float)v[j] * d);
                h8w[(size_t)n * 8 + (idx & 7)] = v;
            }
        }
    }
}

// ---------------------------------------------------------------------------
// E (R0 verbatim, proven): CSR gather + bias + log_softmax. EIGHTH-wave per
// node: 8 lanes x 16 B f16x8 loads. 32 nodes/block, 1563 blocks.
// ---------------------------------------------------------------------------
__global__ __launch_bounds__(256) void kE_agg(const int2* __restrict__ nodeoff2,
                                              const unsigned short* __restrict__ csr,
                                              const __half* __restrict__ h,
                                              const float* __restrict__ bvec,
                                              float* __restrict__ out) {
    const int t = threadIdx.x;
    const int ew = t >> 3, sl = t & 7;       // eighth-wave id / sub-lane
    const int n = blockIdx.x * 32 + ew;
    if (n >= N_NODES) return;                // unit-uniform guard
    const f16x8* __restrict__ h8 = (const f16x8*)h;

    const int2 off = nodeoff2[n];
    const int s0 = off.x, s1 = off.x + off.y;

    const f16x8 hv = h8[(size_t)n * 8 + sl]; // self-loop term (scaled)
    float a[8];
#pragma unroll
    for (int j = 0; j < 8; ++j) a[j] = (float)hv[j];

    int i = s0;
    for (; i + 4 <= s1; i += 4) {
        const int c0 = csr[i + 0];
        const int c1 = csr[i + 1];
        const int c2 = csr[i + 2];
        const int c3 = csr[i + 3];
        const f16x8 v0 = h8[(size_t)c0 * 8 + sl];
        const f16x8 v1 = h8[(size_t)c1 * 8 + sl];
        const f16x8 v2 = h8[(size_t)c2 * 8 + sl];
        const f16x8 v3 = h8[(size_t)c3 * 8 + sl];
#pragma unroll
        for (int j = 0; j < 8; ++j)
            a[j] += (float)v0[j] + (float)v1[j] + (float)v2[j] + (float)v3[j];
    }
    for (; i < s1; ++i) {
        const f16x8 v0 = h8[(size_t)csr[i] * 8 + sl];
#pragma unroll
        for (int j = 0; j < 8; ++j) a[j] += (float)v0[j];
    }

    const float4 b0 = *(const float4*)&bvec[8 * sl];
    const float4 b1 = *(const float4*)&bvec[8 * sl + 4];
    const float di = rsqrtf((float)(off.y + 1));
    float v[8];
    v[0] = a[0] * di + b0.x; v[1] = a[1] * di + b0.y;
    v[2] = a[2] * di + b0.z; v[3] = a[3] * di + b0.w;
    v[4] = a[4] * di + b1.x; v[5] = a[5] * di + b1.y;
    v[6] = a[6] * di + b1.z; v[7] = a[7] * di + b1.w;

    float m = v[0];
#pragma unroll
    for (int j = 1; j < 8; ++j) m = fmaxf(m, v[j]);
#pragma unroll
    for (int o = 4; o > 0; o >>= 1) m = fmaxf(m, __shfl_xor(m, o));
    float s = 0.f;
#pragma unroll
    for (int j = 0; j < 8; ++j) s += __expf(v[j] - m);
#pragma unroll
    for (int o = 4; o > 0; o >>= 1) s += __shfl_xor(s, o);
    const float ls = m + __logf(s);

    float4 o0, o1;
    o0.x = v[0] - ls; o0.y = v[1] - ls; o0.z = v[2] - ls; o0.w = v[3] - ls;
    o1.x = v[4] - ls; o1.y = v[5] - ls; o1.z = v[6] - ls; o1.w = v[7] - ls;
    *(float4*)&out[(size_t)n * DIM_OUT + 8 * sl]     = o0;
    *(float4*)&out[(size_t)n * DIM_OUT + 8 * sl + 4] = o1;
}

// ---------------------------------------------------------------------------
extern "C" void kernel_launch(void* const* d_in, const int* in_sizes, int n_in,
                              void* d_out, int out_size, void* d_ws, size_t ws_size,
                              hipStream_t stream) {
    const float* x  = (const float*)d_in[0];
    const int*   ei = (const int*)d_in[1];   // [2, E]: row0 = src, row1 = dst
    const float* W  = (const float*)d_in[2];
    const float* b  = (const float*)d_in[3];
    float* out = (float*)d_out;

    // workspace (~19 MB of the 256 MB ws):
    char* ws = (char*)d_ws;
    __half*         h        = (__half*)ws;         ws += (size_t)N_NODES * DIM_OUT * sizeof(__half);
    unsigned*       pairs    = (unsigned*)ws;       ws += (size_t)NB2 * RUNTOT * sizeof(unsigned);
    unsigned short* csr      = (unsigned short*)ws; ws += (size_t)NB2 * CAPB * sizeof(unsigned short);
    int2*           nodeoff2 = (int2*)ws;           ws += (size_t)N_NODES * sizeof(int2);
    int*            hist     = (int*)ws;            ws += (size_t)SORTB * HSTRIDE * sizeof(int);

    kFG    <<<SORTB + GEMMB, 256, 0, stream>>>(ei, hist, pairs, x, W, h);
    kSort  <<<NB2, 512, 0, stream>>>(pairs, hist, csr, nodeoff2, h);
    kE_agg <<<NEGRP, 256, 0, stream>>>(nodeoff2, csr, h, b, out);
}

// Round 11
// 117.090 us; speedup vs baseline: 1.1867x; 1.0336x over previous
//
#include <hip/hip_runtime.h>
#include <hip/hip_fp16.h>
#include <cstdint>
#include <cstddef>

#define N_NODES 50000
#define N_EDGES 800000
#define DIM_IN  128
#define DIM_OUT 64

// R10 post-mortem: every FE redesign (R2/R5/R8/R9/R10) lost to R7's simple
// histogram+reserve+scatter — FE line of attack closed. R11 targets the one
// never-isolated cost: kSort's 12.8MB h-rescale pass. kSort now emits
// dinv[] (200KB, free from its LDS bins) and skips the h-pass; kE applies
// dinv[src] in-gather (L2-hot 4B broadcast + FMA, fp32 — numerically
// better than the old pre-rounded fp16 scale). kE unroll 4->8.
#define B2SHIFT 8                                   // 256 nodes per bucket
#define B2NODES 256
#define NB2     ((N_NODES + B2NODES - 1) / B2NODES) // 196 buckets
#define EB      4096                                // edges per front-end tile
#define SORTB   ((N_EDGES + EB - 1) / EB)           // 196 tiles
#define NE4     (N_EDGES / 4)                       // 200000 int4 edge groups
#define CAPB    4864                                // slots/bucket (mean 4082 + 12 sigma)
#define GROWS   128                                 // gemm rows per 256t unit (R0/R7 proven)
#define GEMMB   ((N_NODES + GROWS - 1) / GROWS)     // 391 gemm units
#define GPAD    16                                  // gcnt stride: 1 counter per 64B line
#define NEGRP   ((N_NODES + 31) / 32)               // 1563 kE blocks (32 nodes each)

typedef _Float16 f16x8 __attribute__((ext_vector_type(8)));
typedef float    f32x4 __attribute__((ext_vector_type(4)));

// ---------------------------------------------------------------------------
// FG (R7 verbatim): dual-role dispatch, 256 threads/block, NO grid sync.
//   blocks 0..SORTB-1 : bucket-scatter front-end (histogram/reserve/scatter)
//   blocks SORTB..586 : MFMA gemm writing UNSCALED h = half(x @ W)
// ---------------------------------------------------------------------------
__global__ __launch_bounds__(256) void kFG(const int* __restrict__ ei,
                                           int* __restrict__ gcnt,
                                           unsigned* __restrict__ pairs,
                                           const float* __restrict__ x,
                                           const float* __restrict__ W,
                                           __half* __restrict__ h) {
    const int t = threadIdx.x;
    if (blockIdx.x < SORTB) {
        // ---- front-end tile: histogram -> reserve -> scatter ----
        __shared__ int hcnt[B2NODES];
        __shared__ int cur[B2NODES];
        const int blk = blockIdx.x;
        hcnt[t] = 0;                         // blockDim == B2NODES
        __syncthreads();
        const int4* src4 = (const int4*)ei;
        const int4* dst4 = (const int4*)(ei + N_EDGES);
        const int g0 = blk * (EB / 4);
#pragma unroll
        for (int it = 0; it < EB / 1024; ++it) {
            const int g = g0 + it * 256 + t;
            if (g < NE4) {
                const int4 d = dst4[g];
                atomicAdd(&hcnt[d.x >> B2SHIFT], 1);
                atomicAdd(&hcnt[d.y >> B2SHIFT], 1);
                atomicAdd(&hcnt[d.z >> B2SHIFT], 1);
                atomicAdd(&hcnt[d.w >> B2SHIFT], 1);
            }
        }
        __syncthreads();
        {                                    // reserve: 1 bucket per thread
            const int c = hcnt[t];
            // t >= NB2 has c == 0 -> no OOB atomic (gcnt sized NB2*GPAD)
            const int base = c ? atomicAdd(&gcnt[t * GPAD], c) : 0;
            cur[t] = t * CAPB + base;
        }
        __syncthreads();
#pragma unroll
        for (int it = 0; it < EB / 1024; ++it) {     // scatter (L2-hot reread)
            const int g = g0 + it * 256 + t;
            if (g < NE4) {
                const int4 sv = src4[g];
                const int4 dv = dst4[g];
                int b, p;
                b = dv.x >> B2SHIFT; p = atomicAdd(&cur[b], 1);
                if (p < b * CAPB + CAPB) pairs[p] = ((unsigned)sv.x << 16) | (unsigned)dv.x;
                b = dv.y >> B2SHIFT; p = atomicAdd(&cur[b], 1);
                if (p < b * CAPB + CAPB) pairs[p] = ((unsigned)sv.y << 16) | (unsigned)dv.y;
                b = dv.z >> B2SHIFT; p = atomicAdd(&cur[b], 1);
                if (p < b * CAPB + CAPB) pairs[p] = ((unsigned)sv.z << 16) | (unsigned)dv.z;
                b = dv.w >> B2SHIFT; p = atomicAdd(&cur[b], 1);
                if (p < b * CAPB + CAPB) pairs[p] = ((unsigned)sv.w << 16) | (unsigned)dv.w;
            }
        }
    } else {
        // ---- gemm unit: h[n,:] = half(x[n,:] @ W), UNSCALED (R0 verbatim) ----
        // MFMA 16x16x32_f16: A[m=lane&15][k=quad*8+j]; B[k][n=lane&15];
        // C/D: row=quad*4+reg, col=lane&15 (validated R6-R10).
        const int u = blockIdx.x - SORTB;
        const int w = t >> 6;
        const int l = t & 63;
        const int q = l >> 4;
        const int m16 = l & 15;

        f16x8 bf[4][4];
#pragma unroll
        for (int kc = 0; kc < 4; ++kc)
#pragma unroll
            for (int ct = 0; ct < 4; ++ct) {
                const float* wp = W + (size_t)(kc * 32 + q * 8) * DIM_OUT + ct * 16 + m16;
                f16x8 v;
#pragma unroll
                for (int j = 0; j < 8; ++j) v[j] = (_Float16)wp[(size_t)j * DIM_OUT];
                bf[kc][ct] = v;
            }

        const int base = u * GROWS + w * 32;
#pragma unroll
        for (int rt = 0; rt < 2; ++rt) {
            const int m0 = base + rt * 16;
            int mrow = m0 + m16;
            if (mrow >= N_NODES) mrow = N_NODES - 1;   // clamp (stores guarded)

            f16x8 af[4];
#pragma unroll
            for (int kc = 0; kc < 4; ++kc) {
                const float4* xp = (const float4*)(x + (size_t)mrow * DIM_IN + kc * 32 + q * 8);
                const float4 p0 = xp[0], p1 = xp[1];
                f16x8 a;
                a[0] = (_Float16)p0.x; a[1] = (_Float16)p0.y;
                a[2] = (_Float16)p0.z; a[3] = (_Float16)p0.w;
                a[4] = (_Float16)p1.x; a[5] = (_Float16)p1.y;
                a[6] = (_Float16)p1.z; a[7] = (_Float16)p1.w;
                af[kc] = a;
            }

            f32x4 acc[4];
#pragma unroll
            for (int ct = 0; ct < 4; ++ct) acc[ct] = (f32x4){0.f, 0.f, 0.f, 0.f};
#pragma unroll
            for (int kc = 0; kc < 4; ++kc)
#pragma unroll
                for (int ct = 0; ct < 4; ++ct)
                    acc[ct] = __builtin_amdgcn_mfma_f32_16x16x32_f16(af[kc], bf[kc][ct], acc[ct], 0, 0, 0);

#pragma unroll
            for (int reg = 0; reg < 4; ++reg) {
                const int r = m0 + q * 4 + reg;
                if (r < N_NODES) {
#pragma unroll
                    for (int ct = 0; ct < 4; ++ct)
                        h[(size_t)r * DIM_OUT + ct * 16 + m16] = __float2half(acc[ct][reg]);
                }
            }
        }
    }
}

// ---------------------------------------------------------------------------
// Sort: R7 interior, MINUS the 12.8MB h-rescale pass; emits dinv[] instead
// (one coalesced float per node — degrees are already in the LDS bins).
// ---------------------------------------------------------------------------
__global__ __launch_bounds__(512) void kSort(const unsigned* __restrict__ pairs,
                                             const int* __restrict__ gcnt,
                                             unsigned short* __restrict__ csr,
                                             int2* __restrict__ nodeoff2,
                                             float* __restrict__ dinv) {
    __shared__ int cnt[B2NODES];
    __shared__ int cur[B2NODES];
    __shared__ int wsum[4];
    __shared__ unsigned short lcsr[CAPB];    // 9.7 KB
    const int b = blockIdx.x, t = threadIdx.x;
    const int eb = b * CAPB;
    const int count = min(gcnt[b * GPAD], CAPB);
    const int ee = eb + count;

    if (t < B2NODES) cnt[t] = 0;
    __syncthreads();

    {   // count
        int i = eb + t;
        for (; i + 1536 < ee; i += 2048) {
            const unsigned p0 = pairs[i];
            const unsigned p1 = pairs[i + 512];
            const unsigned p2 = pairs[i + 1024];
            const unsigned p3 = pairs[i + 1536];
            atomicAdd(&cnt[p0 & (B2NODES - 1)], 1);
            atomicAdd(&cnt[p1 & (B2NODES - 1)], 1);
            atomicAdd(&cnt[p2 & (B2NODES - 1)], 1);
            atomicAdd(&cnt[p3 & (B2NODES - 1)], 1);
        }
        for (; i < ee; i += 512) atomicAdd(&cnt[pairs[i] & (B2NODES - 1)], 1);
    }
    __syncthreads();

    // 256-bin exclusive scan: intra-wave shuffle scan + cross-wave combine
    if (t < B2NODES) {
        const int lane = t & 63;
        const int v = cnt[t];
        int xs = v;
#pragma unroll
        for (int off = 1; off < 64; off <<= 1) {
            int y = __shfl_up(xs, off);
            if (lane >= off) xs += y;
        }
        cur[t] = xs;                         // intra-wave inclusive
        if (lane == 63) wsum[t >> 6] = xs;
    }
    __syncthreads();
    if (t == 0) {
        int acc = 0;
#pragma unroll
        for (int w2 = 0; w2 < 4; ++w2) { const int v2 = wsum[w2]; wsum[w2] = acc; acc += v2; }
    }
    __syncthreads();
    if (t < B2NODES) {
        const int v = cnt[t];
        const int excl = cur[t] - v + wsum[t >> 6];
        const int n = (b << B2SHIFT) + t;
        if (n < N_NODES) {
            nodeoff2[n] = make_int2(eb + excl, v);
            dinv[n] = rsqrtf((float)(v + 1));   // src-scale for kE's gather
        }
        cur[t] = excl;                       // bucket-local scatter offsets
    }
    __syncthreads();

    for (int i = eb + t; i < ee; i += 512) { // LDS scatter
        const unsigned p = pairs[i];
        const int q = atomicAdd(&cur[p & (B2NODES - 1)], 1);
        lcsr[q] = (unsigned short)(p >> 16);
    }
    __syncthreads();

    {   // coalesced csr dump (2 ushorts per uint store)
        const int cw = (count + 1) >> 1;
        const unsigned* l32 = (const unsigned*)lcsr;
        unsigned* c32 = (unsigned*)(csr + eb);
        for (int i2 = t; i2 < cw; i2 += 512) c32[i2] = l32[i2];
    }
}

// ---------------------------------------------------------------------------
// E: CSR gather + per-src dinv (fp32 FMA, L2-hot 200KB array) + bias +
// log_softmax. Eighth-wave per node; 8-deep unroll (mean deg 16 -> 2 full
// iterations, 2x outstanding gathers vs R7's 4-deep).
// ---------------------------------------------------------------------------
__global__ __launch_bounds__(256) void kE_agg(const int2* __restrict__ nodeoff2,
                                              const unsigned short* __restrict__ csr,
                                              const __half* __restrict__ h,
                                              const float* __restrict__ dinv,
                                              const float* __restrict__ bvec,
                                              float* __restrict__ out) {
    const int t = threadIdx.x;
    const int ew = t >> 3, sl = t & 7;       // eighth-wave id / sub-lane
    const int n = blockIdx.x * 32 + ew;
    if (n >= N_NODES) return;                // unit-uniform guard
    const f16x8* __restrict__ h8 = (const f16x8*)h;

    const int2 off = nodeoff2[n];
    const int s0 = off.x, s1 = off.x + off.y;
    const float di = rsqrtf((float)(off.y + 1));   // == dinv[n]

    const f16x8 hv = h8[(size_t)n * 8 + sl]; // self-loop term (unscaled h)
    float a[8];
#pragma unroll
    for (int j = 0; j < 8; ++j) a[j] = (float)hv[j] * di;

    int i = s0;
    for (; i + 8 <= s1; i += 8) {
        int   c[8];
        float d[8];
        f16x8 v[8];
#pragma unroll
        for (int j = 0; j < 8; ++j) c[j] = csr[i + j];
#pragma unroll
        for (int j = 0; j < 8; ++j) d[j] = dinv[c[j]];         // L2-hot broadcast
#pragma unroll
        for (int j = 0; j < 8; ++j) v[j] = h8[(size_t)c[j] * 8 + sl];
#pragma unroll
        for (int j = 0; j < 8; ++j)
#pragma unroll
            for (int k = 0; k < 8; ++k) a[k] += (float)v[j][k] * d[j];
    }
    for (; i + 4 <= s1; i += 4) {
        const int c0 = csr[i + 0], c1 = csr[i + 1];
        const int c2 = csr[i + 2], c3 = csr[i + 3];
        const float d0 = dinv[c0], d1 = dinv[c1], d2 = dinv[c2], d3 = dinv[c3];
        const f16x8 v0 = h8[(size_t)c0 * 8 + sl];
        const f16x8 v1 = h8[(size_t)c1 * 8 + sl];
        const f16x8 v2 = h8[(size_t)c2 * 8 + sl];
        const f16x8 v3 = h8[(size_t)c3 * 8 + sl];
#pragma unroll
        for (int j = 0; j < 8; ++j)
            a[j] += (float)v0[j] * d0 + (float)v1[j] * d1
                  + (float)v2[j] * d2 + (float)v3[j] * d3;
    }
    for (; i < s1; ++i) {
        const int c = csr[i];
        const float d = dinv[c];
        const f16x8 v0 = h8[(size_t)c * 8 + sl];
#pragma unroll
        for (int j = 0; j < 8; ++j) a[j] += (float)v0[j] * d;
    }

    const float4 b0 = *(const float4*)&bvec[8 * sl];
    const float4 b1 = *(const float4*)&bvec[8 * sl + 4];
    float v[8];
    v[0] = a[0] * di + b0.x; v[1] = a[1] * di + b0.y;
    v[2] = a[2] * di + b0.z; v[3] = a[3] * di + b0.w;
    v[4] = a[4] * di + b1.x; v[5] = a[5] * di + b1.y;
    v[6] = a[6] * di + b1.z; v[7] = a[7] * di + b1.w;

    float m = v[0];
#pragma unroll
    for (int j = 1; j < 8; ++j) m = fmaxf(m, v[j]);
#pragma unroll
    for (int o = 4; o > 0; o >>= 1) m = fmaxf(m, __shfl_xor(m, o));
    float s = 0.f;
#pragma unroll
    for (int j = 0; j < 8; ++j) s += __expf(v[j] - m);
#pragma unroll
    for (int o = 4; o > 0; o >>= 1) s += __shfl_xor(s, o);
    const float ls = m + __logf(s);

    float4 o0, o1;
    o0.x = v[0] - ls; o0.y = v[1] - ls; o0.z = v[2] - ls; o0.w = v[3] - ls;
    o1.x = v[4] - ls; o1.y = v[5] - ls; o1.z = v[6] - ls; o1.w = v[7] - ls;
    *(float4*)&out[(size_t)n * DIM_OUT + 8 * sl]     = o0;
    *(float4*)&out[(size_t)n * DIM_OUT + 8 * sl + 4] = o1;
}

// ---------------------------------------------------------------------------
extern "C" void kernel_launch(void* const* d_in, const int* in_sizes, int n_in,
                              void* d_out, int out_size, void* d_ws, size_t ws_size,
                              hipStream_t stream) {
    const float* x  = (const float*)d_in[0];
    const int*   ei = (const int*)d_in[1];   // [2, E]: row0 = src, row1 = dst
    const float* W  = (const float*)d_in[2];
    const float* b  = (const float*)d_in[3];
    float* out = (float*)d_out;

    // workspace (~13 MB of the 256 MB ws):
    char* ws = (char*)d_ws;
    __half*         h        = (__half*)ws;         ws += (size_t)N_NODES * DIM_OUT * sizeof(__half);
    unsigned*       pairs    = (unsigned*)ws;       ws += (size_t)NB2 * CAPB * sizeof(unsigned);
    unsigned short* csr      = (unsigned short*)ws; ws += (size_t)NB2 * CAPB * sizeof(unsigned short);
    int2*           nodeoff2 = (int2*)ws;           ws += (size_t)N_NODES * sizeof(int2);
    float*          dinv     = (float*)ws;          ws += (size_t)N_NODES * sizeof(float);
    int*            gcnt     = (int*)ws;            ws += (size_t)NB2 * GPAD * sizeof(int);

    hipMemsetAsync(gcnt, 0, (size_t)NB2 * GPAD * sizeof(int), stream);
    kFG    <<<SORTB + GEMMB, 256, 0, stream>>>(ei, gcnt, pairs, x, W, h);
    kSort  <<<NB2, 512, 0, stream>>>(pairs, gcnt, csr, nodeoff2, dinv);
    kE_agg <<<NEGRP, 256, 0, stream>>>(nodeoff2, csr, h, dinv, b, out);
}

// Round 12
// 114.131 us; speedup vs baseline: 1.2174x; 1.0259x over previous
//
#include <hip/hip_runtime.h>
#include <hip/hip_fp16.h>
#include <cstdint>
#include <cstddef>

#define N_NODES 50000
#define N_EDGES 800000
#define DIM_IN  128
#define DIM_OUT 64

// R12: R7 champion + FE micro-restructure (the one untried surface):
//  - edges held in REGISTERS across all three FE phases (no L2 re-read)
//  - scatter as batched {16 independent LDS atomics -> 16 independent
//    stores} instead of 16 serialized atomic->store chains
//  - k_zero dispatch replaced by hipMemsetAsync
//  - kE 8-deep unroll (2x outstanding gathers)
// kSort + GEMM role verbatim R7.
#define B2SHIFT 8                                   // 256 nodes per bucket
#define B2NODES 256
#define NB2     ((N_NODES + B2NODES - 1) / B2NODES) // 196 buckets
#define EB      4096                                // edges per front-end tile
#define SORTB   ((N_EDGES + EB - 1) / EB)           // 196 tiles
#define NE4     (N_EDGES / 4)                       // 200000 int4 edge groups
#define CAPB    4864                                // slots/bucket (mean 4082 + 12 sigma)
#define GROWS   128                                 // gemm rows per 256t unit (R0/R7 proven)
#define GEMMB   ((N_NODES + GROWS - 1) / GROWS)     // 391 gemm units
#define GPAD    16                                  // gcnt stride: 1 counter per 64B line
#define NEGRP   ((N_NODES + 31) / 32)               // 1563 kE blocks (32 nodes each)

typedef _Float16 f16x8 __attribute__((ext_vector_type(8)));
typedef float    f32x4 __attribute__((ext_vector_type(4)));

// ---------------------------------------------------------------------------
// FG: dual-role dispatch, 256 threads/block, NO grid sync.
//   blocks 0..SORTB-1 : FE tile, register-resident edges, batched scatter.
//   blocks SORTB..586 : MFMA gemm (R0 verbatim) writing UNSCALED h.
// ---------------------------------------------------------------------------
__global__ __launch_bounds__(256) void kFG(const int* __restrict__ ei,
                                           int* __restrict__ gcnt,
                                           unsigned* __restrict__ pairs,
                                           const float* __restrict__ x,
                                           const float* __restrict__ W,
                                           __half* __restrict__ h) {
    const int t = threadIdx.x;
    if (blockIdx.x < SORTB) {
        // ---- front-end tile: one edge read, batched scatter ----
        __shared__ int hcnt[B2NODES];
        __shared__ int cur[B2NODES];
        const int blk = blockIdx.x;
        hcnt[t] = 0;                         // blockDim == B2NODES
        __syncthreads();
        const int4* src4 = (const int4*)ei;
        const int4* dst4 = (const int4*)(ei + N_EDGES);
        const int g0 = blk * (EB / 4);

        int4 dv[4], sv[4];
        bool live[4];
#pragma unroll
        for (int it = 0; it < 4; ++it) {     // load ALL edges to registers
            const int g = g0 + it * 256 + t;
            live[it] = (g < NE4);
            if (live[it]) { dv[it] = dst4[g]; sv[it] = src4[g]; }
        }
#pragma unroll
        for (int it = 0; it < 4; ++it) {     // histogram from registers
            if (live[it]) {
                atomicAdd(&hcnt[dv[it].x >> B2SHIFT], 1);
                atomicAdd(&hcnt[dv[it].y >> B2SHIFT], 1);
                atomicAdd(&hcnt[dv[it].z >> B2SHIFT], 1);
                atomicAdd(&hcnt[dv[it].w >> B2SHIFT], 1);
            }
        }
        __syncthreads();
        {                                    // reserve: 1 bucket per thread
            const int c = hcnt[t];
            // t >= NB2 has c == 0 -> no OOB atomic (gcnt sized NB2*GPAD)
            const int base = c ? atomicAdd(&gcnt[t * GPAD], c) : 0;
            cur[t] = t * CAPB + base;
        }
        __syncthreads();
        {   // batched scatter: 16 independent LDS atomics, then 16 stores
            int pos[16];
            int bb[16];
#pragma unroll
            for (int it = 0; it < 4; ++it) {
                if (live[it]) {
                    bb[it * 4 + 0] = dv[it].x >> B2SHIFT;
                    bb[it * 4 + 1] = dv[it].y >> B2SHIFT;
                    bb[it * 4 + 2] = dv[it].z >> B2SHIFT;
                    bb[it * 4 + 3] = dv[it].w >> B2SHIFT;
#pragma unroll
                    for (int c2 = 0; c2 < 4; ++c2)
                        pos[it * 4 + c2] = atomicAdd(&cur[bb[it * 4 + c2]], 1);
                }
            }
#pragma unroll
            for (int it = 0; it < 4; ++it) {
                if (live[it]) {
                    const int p0 = pos[it * 4 + 0], p1 = pos[it * 4 + 1];
                    const int p2 = pos[it * 4 + 2], p3 = pos[it * 4 + 3];
                    if (p0 < bb[it * 4 + 0] * CAPB + CAPB)
                        pairs[p0] = ((unsigned)sv[it].x << 16) | (unsigned)dv[it].x;
                    if (p1 < bb[it * 4 + 1] * CAPB + CAPB)
                        pairs[p1] = ((unsigned)sv[it].y << 16) | (unsigned)dv[it].y;
                    if (p2 < bb[it * 4 + 2] * CAPB + CAPB)
                        pairs[p2] = ((unsigned)sv[it].z << 16) | (unsigned)dv[it].z;
                    if (p3 < bb[it * 4 + 3] * CAPB + CAPB)
                        pairs[p3] = ((unsigned)sv[it].w << 16) | (unsigned)dv[it].w;
                }
            }
        }
    } else {
        // ---- gemm unit: h[n,:] = half(x[n,:] @ W), UNSCALED (R0 verbatim) ----
        // MFMA 16x16x32_f16: A[m=lane&15][k=quad*8+j]; B[k][n=lane&15];
        // C/D: row=quad*4+reg, col=lane&15 (validated R6-R10).
        const int u = blockIdx.x - SORTB;
        const int w = t >> 6;
        const int l = t & 63;
        const int q = l >> 4;
        const int m16 = l & 15;

        f16x8 bf[4][4];
#pragma unroll
        for (int kc = 0; kc < 4; ++kc)
#pragma unroll
            for (int ct = 0; ct < 4; ++ct) {
                const float* wp = W + (size_t)(kc * 32 + q * 8) * DIM_OUT + ct * 16 + m16;
                f16x8 v;
#pragma unroll
                for (int j = 0; j < 8; ++j) v[j] = (_Float16)wp[(size_t)j * DIM_OUT];
                bf[kc][ct] = v;
            }

        const int base = u * GROWS + w * 32;
#pragma unroll
        for (int rt = 0; rt < 2; ++rt) {
            const int m0 = base + rt * 16;
            int mrow = m0 + m16;
            if (mrow >= N_NODES) mrow = N_NODES - 1;   // clamp (stores guarded)

            f16x8 af[4];
#pragma unroll
            for (int kc = 0; kc < 4; ++kc) {
                const float4* xp = (const float4*)(x + (size_t)mrow * DIM_IN + kc * 32 + q * 8);
                const float4 p0 = xp[0], p1 = xp[1];
                f16x8 a;
                a[0] = (_Float16)p0.x; a[1] = (_Float16)p0.y;
                a[2] = (_Float16)p0.z; a[3] = (_Float16)p0.w;
                a[4] = (_Float16)p1.x; a[5] = (_Float16)p1.y;
                a[6] = (_Float16)p1.z; a[7] = (_Float16)p1.w;
                af[kc] = a;
            }

            f32x4 acc[4];
#pragma unroll
            for (int ct = 0; ct < 4; ++ct) acc[ct] = (f32x4){0.f, 0.f, 0.f, 0.f};
#pragma unroll
            for (int kc = 0; kc < 4; ++kc)
#pragma unroll
                for (int ct = 0; ct < 4; ++ct)
                    acc[ct] = __builtin_amdgcn_mfma_f32_16x16x32_f16(af[kc], bf[kc][ct], acc[ct], 0, 0, 0);

#pragma unroll
            for (int reg = 0; reg < 4; ++reg) {
                const int r = m0 + q * 4 + reg;
                if (r < N_NODES) {
#pragma unroll
                    for (int ct = 0; ct < 4; ++ct)
                        h[(size_t)r * DIM_OUT + ct * 16 + m16] = __float2half(acc[ct][reg]);
                }
            }
        }
    }
}

// ---------------------------------------------------------------------------
// Sort (R7 verbatim): one block per 256-node bucket (512 threads):
//   count -> scan -> LDS scatter -> coalesced csr dump + nodeoff2 +
//   in-place h *= rsqrt(deg+1).
// ---------------------------------------------------------------------------
__global__ __launch_bounds__(512) void kSort(const unsigned* __restrict__ pairs,
                                             const int* __restrict__ gcnt,
                                             unsigned short* __restrict__ csr,
                                             int2* __restrict__ nodeoff2,
                                             __half* __restrict__ h) {
    __shared__ int cnt[B2NODES];
    __shared__ int cur[B2NODES];
    __shared__ float sdinv[B2NODES];
    __shared__ int wsum[4];
    __shared__ unsigned short lcsr[CAPB];    // 9.7 KB
    const int b = blockIdx.x, t = threadIdx.x;
    const int eb = b * CAPB;
    const int count = min(gcnt[b * GPAD], CAPB);
    const int ee = eb + count;

    if (t < B2NODES) cnt[t] = 0;
    __syncthreads();

    {   // count
        int i = eb + t;
        for (; i + 1536 < ee; i += 2048) {
            const unsigned p0 = pairs[i];
            const unsigned p1 = pairs[i + 512];
            const unsigned p2 = pairs[i + 1024];
            const unsigned p3 = pairs[i + 1536];
            atomicAdd(&cnt[p0 & (B2NODES - 1)], 1);
            atomicAdd(&cnt[p1 & (B2NODES - 1)], 1);
            atomicAdd(&cnt[p2 & (B2NODES - 1)], 1);
            atomicAdd(&cnt[p3 & (B2NODES - 1)], 1);
        }
        for (; i < ee; i += 512) atomicAdd(&cnt[pairs[i] & (B2NODES - 1)], 1);
    }
    __syncthreads();

    // 256-bin exclusive scan: intra-wave shuffle scan + cross-wave combine
    if (t < B2NODES) {
        const int lane = t & 63;
        const int v = cnt[t];
        int xs = v;
#pragma unroll
        for (int off = 1; off < 64; off <<= 1) {
            int y = __shfl_up(xs, off);
            if (lane >= off) xs += y;
        }
        cur[t] = xs;                         // intra-wave inclusive
        if (lane == 63) wsum[t >> 6] = xs;
    }
    __syncthreads();
    if (t == 0) {
        int acc = 0;
#pragma unroll
        for (int w2 = 0; w2 < 4; ++w2) { const int v2 = wsum[w2]; wsum[w2] = acc; acc += v2; }
    }
    __syncthreads();
    if (t < B2NODES) {
        const int v = cnt[t];
        const int excl = cur[t] - v + wsum[t >> 6];
        sdinv[t] = rsqrtf((float)(v + 1));
        const int n = (b << B2SHIFT) + t;
        if (n < N_NODES) nodeoff2[n] = make_int2(eb + excl, v);
        cur[t] = excl;                       // bucket-local scatter offsets
    }
    __syncthreads();

    for (int i = eb + t; i < ee; i += 512) { // LDS scatter
        const unsigned p = pairs[i];
        const int q = atomicAdd(&cur[p & (B2NODES - 1)], 1);
        lcsr[q] = (unsigned short)(p >> 16);
    }
    __syncthreads();

    {   // coalesced csr dump (2 ushorts per uint store)
        const int cw = (count + 1) >> 1;
        const unsigned* l32 = (const unsigned*)lcsr;
        unsigned* c32 = (unsigned*)(csr + eb);
        for (int i2 = t; i2 < cw; i2 += 512) c32[i2] = l32[i2];
    }
    {   // in-place h-scale for this bucket's 256 nodes (contiguous 32 KB)
        f16x8* h8w = (f16x8*)h;
        for (int idx = t; idx < B2NODES * 8; idx += 512) {
            const int r = idx >> 3;
            const int n = (b << B2SHIFT) + r;
            if (n < N_NODES) {
                const float d = sdinv[r];
                f16x8 v = h8w[(size_t)n * 8 + (idx & 7)];
#pragma unroll
                for (int j = 0; j < 8; ++j) v[j] = (_Float16)((float)v[j] * d);
                h8w[(size_t)n * 8 + (idx & 7)] = v;
            }
        }
    }
}

// ---------------------------------------------------------------------------
// E: CSR gather + bias + log_softmax (pre-scaled h). Eighth-wave per node;
// 8-deep unroll (2x outstanding gathers vs R7's 4-deep).
// ---------------------------------------------------------------------------
__global__ __launch_bounds__(256) void kE_agg(const int2* __restrict__ nodeoff2,
                                              const unsigned short* __restrict__ csr,
                                              const __half* __restrict__ h,
                                              const float* __restrict__ bvec,
                                              float* __restrict__ out) {
    const int t = threadIdx.x;
    const int ew = t >> 3, sl = t & 7;       // eighth-wave id / sub-lane
    const int n = blockIdx.x * 32 + ew;
    if (n >= N_NODES) return;                // unit-uniform guard
    const f16x8* __restrict__ h8 = (const f16x8*)h;

    const int2 off = nodeoff2[n];
    const int s0 = off.x, s1 = off.x + off.y;

    const f16x8 hv = h8[(size_t)n * 8 + sl]; // self-loop term (scaled)
    float a[8];
#pragma unroll
    for (int j = 0; j < 8; ++j) a[j] = (float)hv[j];

    int i = s0;
    for (; i + 8 <= s1; i += 8) {
        int c[8];
        f16x8 v[8];
#pragma unroll
        for (int j = 0; j < 8; ++j) c[j] = csr[i + j];
#pragma unroll
        for (int j = 0; j < 8; ++j) v[j] = h8[(size_t)c[j] * 8 + sl];
#pragma unroll
        for (int j = 0; j < 8; ++j)
#pragma unroll
            for (int k = 0; k < 8; ++k) a[k] += (float)v[j][k];
    }
    for (; i + 4 <= s1; i += 4) {
        const int c0 = csr[i + 0];
        const int c1 = csr[i + 1];
        const int c2 = csr[i + 2];
        const int c3 = csr[i + 3];
        const f16x8 v0 = h8[(size_t)c0 * 8 + sl];
        const f16x8 v1 = h8[(size_t)c1 * 8 + sl];
        const f16x8 v2 = h8[(size_t)c2 * 8 + sl];
        const f16x8 v3 = h8[(size_t)c3 * 8 + sl];
#pragma unroll
        for (int j = 0; j < 8; ++j)
            a[j] += (float)v0[j] + (float)v1[j] + (float)v2[j] + (float)v3[j];
    }
    for (; i < s1; ++i) {
        const f16x8 v0 = h8[(size_t)csr[i] * 8 + sl];
#pragma unroll
        for (int j = 0; j < 8; ++j) a[j] += (float)v0[j];
    }

    const float4 b0 = *(const float4*)&bvec[8 * sl];
    const float4 b1 = *(const float4*)&bvec[8 * sl + 4];
    const float di = rsqrtf((float)(off.y + 1));
    float v[8];
    v[0] = a[0] * di + b0.x; v[1] = a[1] * di + b0.y;
    v[2] = a[2] * di + b0.z; v[3] = a[3] * di + b0.w;
    v[4] = a[4] * di + b1.x; v[5] = a[5] * di + b1.y;
    v[6] = a[6] * di + b1.z; v[7] = a[7] * di + b1.w;

    float m = v[0];
#pragma unroll
    for (int j = 1; j < 8; ++j) m = fmaxf(m, v[j]);
#pragma unroll
    for (int o = 4; o > 0; o >>= 1) m = fmaxf(m, __shfl_xor(m, o));
    float s = 0.f;
#pragma unroll
    for (int j = 0; j < 8; ++j) s += __expf(v[j] - m);
#pragma unroll
    for (int o = 4; o > 0; o >>= 1) s += __shfl_xor(s, o);
    const float ls = m + __logf(s);

    float4 o0, o1;
    o0.x = v[0] - ls; o0.y = v[1] - ls; o0.z = v[2] - ls; o0.w = v[3] - ls;
    o1.x = v[4] - ls; o1.y = v[5] - ls; o1.z = v[6] - ls; o1.w = v[7] - ls;
    *(float4*)&out[(size_t)n * DIM_OUT + 8 * sl]     = o0;
    *(float4*)&out[(size_t)n * DIM_OUT + 8 * sl + 4] = o1;
}

// ---------------------------------------------------------------------------
extern "C" void kernel_launch(void* const* d_in, const int* in_sizes, int n_in,
                              void* d_out, int out_size, void* d_ws, size_t ws_size,
                              hipStream_t stream) {
    const float* x  = (const float*)d_in[0];
    const int*   ei = (const int*)d_in[1];   // [2, E]: row0 = src, row1 = dst
    const float* W  = (const float*)d_in[2];
    const float* b  = (const float*)d_in[3];
    float* out = (float*)d_out;

    // workspace (~13 MB of the 256 MB ws):
    char* ws = (char*)d_ws;
    __half*         h        = (__half*)ws;         ws += (size_t)N_NODES * DIM_OUT * sizeof(__half);
    unsigned*       pairs    = (unsigned*)ws;       ws += (size_t)NB2 * CAPB * sizeof(unsigned);
    unsigned short* csr      = (unsigned short*)ws; ws += (size_t)NB2 * CAPB * sizeof(unsigned short);
    int2*           nodeoff2 = (int2*)ws;           ws += (size_t)N_NODES * sizeof(int2);
    int*            gcnt     = (int*)ws;            ws += (size_t)NB2 * GPAD * sizeof(int);

    hipMemsetAsync(gcnt, 0, (size_t)NB2 * GPAD * sizeof(int), stream);
    kFG    <<<SORTB + GEMMB, 256, 0, stream>>>(ei, gcnt, pairs, x, W, h);
    kSort  <<<NB2, 512, 0, stream>>>(pairs, gcnt, csr, nodeoff2, h);
    kE_agg <<<NEGRP, 256, 0, stream>>>(nodeoff2, csr, h, b, out);
}